// Round 5
// baseline (199.598 us; speedup 1.0000x reference)
//
#include <hip/hip_runtime.h>

#define EPS 1e-10f
#define HALF_LN2PI 0.91893853320467274f

// b=16, win=14, w=6, ww=36, B_T=32, K=3, Bkk=288 (=i), C_T=32, HH=16
// W flat: [i=288][c=32][hr=4][m=4]
// Pt per (bb,p): [i=288][hc=4][m=4] = patchflat[base(p)+m*4+hc], base(p)=(p/6)*96+(p%6)*16
//
// Grid (m/e): 2304 blocks = (blk = bb*36+p)*4 + iq, 128 threads (2 waves).
// Wave handles 36 i: i = iq*72 + wave*36 + t. 9 blocks/CU, 18 waves/CU ->
// ALL blocks resident, no straggler round.
// lane = cl*4+hr; thread covers c in {cl, cl+16}, 4 hc each.
// Mpart[bid][k*64+lane], k: [0..3]=S1a [4..7]=S2a [8..11]=S1b [12..15]=S2b [16]=sRa [17]=sRb
// f_pass reduces Mpart over the 4 iq partials and writes stats IN PLACE at
// Mpart[blk*4608 + {0:mu, 512:n2, 1024:hl, 1536:a}] (registers buffered, vmcnt-fenced).

template <int IT>
__global__ __launch_bounds__(128)
void m_pass(const float* __restrict__ poses, const float* __restrict__ acts,
            float* __restrict__ Ptg, float* __restrict__ actp,
            const float* __restrict__ W,
            const float* __restrict__ ap_buf, const float* __restrict__ denom_prev,
            float* __restrict__ Mpart)
{
    __shared__ __align__(16) float Pt_lds[1152];   // 72 i x 16
    __shared__ float act_lds[72];
    __shared__ float invd_lds[72];
    __shared__ __align__(16) float red[1152];

    const int tid  = threadIdx.x;
    const int wave = tid >> 6, lane = tid & 63;
    const int cl   = lane >> 2;
    const int bid  = blockIdx.x;
    const int blk  = bid >> 2, iq = bid & 3;
    const int bb   = blk / 36, p = blk - bb * 36;
    const int i0   = iq * 72;
    const size_t pbase  = (size_t)blk * 4608;
    const size_t apbase = (size_t)blk * 9216;

    if (IT == 0) {
        const int base = (p / 6) * 96 + (p % 6) * 16;
        for (int e = tid; e < 1152; e += 128) {
            int il = e >> 4, j = e & 15;
            int i = i0 + il;
            int hc = j >> 2, m = j & 3;
            int f = base + m * 4 + hc;              // flat (h,s)
            int h = f / 36, sp = f - h * 36;
            int y = sp / 6, x = sp - y * 6;
            int B = i / 9, kk = i - B * 9;
            int ki = kk / 3, kj = kk - ki * 3;
            float v = poses[(size_t)((bb * 512 + h * 32 + B) * 14 + 2 * x + ki) * 14 + 2 * y + kj];
            Pt_lds[e] = v;
            Ptg[pbase + (size_t)i0 * 16 + e] = v;
        }
        const int y = p / 6, x = p - y * 6;
        for (int e = tid; e < 72; e += 128) {
            int i = i0 + e;
            int B = i / 9, kk = i - B * 9;
            int ki = kk / 3, kj = kk - ki * 3;
            float v = acts[(size_t)((bb * 32 + B) * 14 + 2 * x + ki) * 14 + 2 * y + kj];
            act_lds[e] = v;
            actp[blk * 288 + i] = v;
        }
    } else {
        const float4* src = (const float4*)(Ptg + pbase + (size_t)i0 * 16);
        float4* dst = (float4*)Pt_lds;
        for (int e = tid; e < 288; e += 128) dst[e] = src[e];
        for (int e = tid; e < 72; e += 128) {
            act_lds[e]  = actp[blk * 288 + i0 + e];
            invd_lds[e] = 1.0f / (denom_prev[bb * 288 + i0 + e] + EPS);
        }
    }
    __syncthreads();

    float acc[18];
#pragma unroll
    for (int k = 0; k < 18; ++k) acc[k] = 0.f;

    const float* Wt = W + (size_t)(i0 + wave * 36) * 512 + (lane << 2);
#pragma unroll 6
    for (int t = 0; t < 36; ++t) {
        const int il = wave * 36 + t;
        const float4 wva = *(const float4*)(Wt + (size_t)t * 512);
        const float4 wvb = *(const float4*)(Wt + (size_t)t * 512 + 256);
        float Ra, Rb;
        if (IT == 0) {
            Ra = 1.0f / 32.0f; Rb = 1.0f / 32.0f;
        } else {
            const int i = i0 + il;
            const float inv = invd_lds[il];
            Ra = fmaf(ap_buf[apbase + (size_t)i * 32 + cl],      inv, EPS);
            Rb = fmaf(ap_buf[apbase + (size_t)i * 32 + cl + 16], inv, EPS);
        }
        const float a_in = act_lds[il];
        const float R4a = Ra * a_in, R4b = Rb * a_in;
        acc[16] += R4a; acc[17] += R4b;
#pragma unroll
        for (int hc = 0; hc < 4; ++hc) {
            const float4 pv = *(const float4*)&Pt_lds[il * 16 + hc * 4];
            float Va = wva.x * pv.x + wva.y * pv.y + wva.z * pv.z + wva.w * pv.w;
            float Vb = wvb.x * pv.x + wvb.y * pv.y + wvb.z * pv.z + wvb.w * pv.w;
            acc[hc]      = fmaf(R4a, Va, acc[hc]);
            acc[4 + hc]  = fmaf(R4a * Va, Va, acc[4 + hc]);
            acc[8 + hc]  = fmaf(R4b, Vb, acc[8 + hc]);
            acc[12 + hc] = fmaf(R4b * Vb, Vb, acc[12 + hc]);
        }
    }

    if (wave == 1) {
#pragma unroll
        for (int k = 0; k < 18; ++k) red[lane * 18 + k] = acc[k];
    }
    __syncthreads();
    if (wave == 0) {
        float* mp = Mpart + (size_t)bid * 1152;
#pragma unroll
        for (int k = 0; k < 18; ++k)
            mp[k * 64 + lane] = acc[k] + red[lane * 18 + k];
    }
}

template <int FINAL>
__global__ __launch_bounds__(64)
void f_pass(float* __restrict__ Mpart, const float* __restrict__ beta_v,
            const float* __restrict__ beta_a, const float* __restrict__ lambda_p,
            float* __restrict__ d_out)
{
    const int lane = threadIdx.x;
    const int cl = lane >> 2, hr = lane & 3;
    const int blk = blockIdx.x;
    const int bb = blk / 36, p = blk - bb * 36;
    float* mp = Mpart + (size_t)blk * 4608;

    float s[18];
#pragma unroll
    for (int k = 0; k < 18; ++k)
        s[k] = mp[k * 64 + lane] + mp[1152 + k * 64 + lane]
             + mp[2304 + k * 64 + lane] + mp[3456 + k * 64 + lane];

    const float lam = lambda_p[0];
    float muv[8], n2v[8], hlv[8], av[2];
#pragma unroll
    for (int q = 0; q < 2; ++q) {
        const int c = cl + q * 16;
        const float sR = s[16 + q];
        float ls = 0.f;
#pragma unroll
        for (int hc = 0; hc < 4; ++hc) {
            const float S1 = s[q * 8 + hc];
            const float S2 = s[q * 8 + 4 + hc];
            const float mu = S1 / sR;
            float ss = S2 / sR - mu * mu;
            ss = fmaxf(ss, 1e-30f);
            muv[q * 4 + hc] = mu;
            n2v[q * 4 + hc] = -0.5f / ss;
            hlv[q * 4 + hc] = -0.5f * __logf(ss) - HALF_LN2PI;
            ls += __logf(sqrtf(ss) + EPS);
        }
        ls += __shfl_xor(ls, 1);
        ls += __shfl_xor(ls, 2);
        const float cost = sR * (16.0f * beta_v[c] + ls);
        av[q] = 1.0f / (1.0f + __expf(-lam * (beta_a[c] - cost)));
    }

    if (FINAL) {
#pragma unroll
        for (int q = 0; q < 2; ++q) {
            const int c = cl + q * 16;
#pragma unroll
            for (int hc = 0; hc < 4; ++hc)
                d_out[(size_t)bb * 18432 + (size_t)(c * 36 + p) * 16 + hr * 4 + hc] = muv[q * 4 + hc];
            if (hr == 0)
                d_out[294912 + (size_t)bb * 1152 + c * 36 + p] = av[q];
        }
    } else {
        // stats written IN PLACE over Mpart[blk]. All stored values depend on all
        // loads; fence anyway so no store can pass an in-flight sibling-lane load.
        asm volatile("s_waitcnt vmcnt(0)" ::: "memory");
#pragma unroll
        for (int q = 0; q < 2; ++q) {
#pragma unroll
            for (int hc = 0; hc < 4; ++hc) {
                const int ix = lane * 4 + q * 256 + hc;
                mp[ix]        = muv[q * 4 + hc];
                mp[512 + ix]  = n2v[q * 4 + hc];
                mp[1024 + ix] = hlv[q * 4 + hc];
            }
            if (hr == 0) mp[1536 + cl + q * 16] = av[q];
        }
    }
}

__global__ __launch_bounds__(128)
void e_pass(const float* __restrict__ Ptg, const float* __restrict__ Mpart,
            const float* __restrict__ W,
            float* __restrict__ ap_buf, float* __restrict__ denom_next)
{
    __shared__ __align__(16) float Pt_lds[1152];

    const int tid  = threadIdx.x;
    const int wave = tid >> 6, lane = tid & 63;
    const int cl   = lane >> 2, hr = lane & 3;
    const int bid  = blockIdx.x;
    const int blk  = bid >> 2, iq = bid & 3;
    const int bb   = blk / 36;
    const int i0   = iq * 72;
    const size_t pbase  = (size_t)blk * 4608;
    const size_t apbase = (size_t)blk * 9216;

    {
        const float4* src = (const float4*)(Ptg + pbase + (size_t)i0 * 16);
        float4* dst = (float4*)Pt_lds;
        for (int e = tid; e < 288; e += 128) dst[e] = src[e];
    }

    // stats straight to registers (written by f_pass into Mpart[blk])
    const float* st = Mpart + (size_t)blk * 4608;
    __align__(16) float mua[4], mub[4], na[4], nb[4], ha[4], hb[4];
    *(float4*)mua = *(const float4*)&st[lane * 4];
    *(float4*)mub = *(const float4*)&st[lane * 4 + 256];
    *(float4*)na  = *(const float4*)&st[512 + lane * 4];
    *(float4*)nb  = *(const float4*)&st[512 + lane * 4 + 256];
    *(float4*)ha  = *(const float4*)&st[1024 + lane * 4];
    *(float4*)hb  = *(const float4*)&st[1024 + lane * 4 + 256];
    const float aca = st[1536 + cl], acb = st[1536 + cl + 16];
    __syncthreads();

    const float* Wt = W + (size_t)(i0 + wave * 36) * 512 + (lane << 2);
#pragma unroll 6
    for (int t = 0; t < 36; ++t) {
        const int il = wave * 36 + t;
        const int i = i0 + il;
        const float4 wva = *(const float4*)(Wt + (size_t)t * 512);
        const float4 wvb = *(const float4*)(Wt + (size_t)t * 512 + 256);
        float pea = 0.f, peb = 0.f;
#pragma unroll
        for (int hc = 0; hc < 4; ++hc) {
            const float4 pv = *(const float4*)&Pt_lds[il * 16 + hc * 4];
            float Va = wva.x * pv.x + wva.y * pv.y + wva.z * pv.z + wva.w * pv.w;
            float Vb = wvb.x * pv.x + wvb.y * pv.y + wvb.z * pv.z + wvb.w * pv.w;
            float da = Va - mua[hc];
            float db = Vb - mub[hc];
            pea += __expf(fmaf(da * da, na[hc], ha[hc]));
            peb += __expf(fmaf(db * db, nb[hc], hb[hc]));
        }
        pea += __shfl_xor(pea, 1);
        pea += __shfl_xor(pea, 2);
        peb += __shfl_xor(peb, 1);
        peb += __shfl_xor(peb, 2);
        const float apa = aca * pea;
        const float apb = acb * peb;
        if (hr == 0) {
            ap_buf[apbase + (size_t)i * 32 + cl]      = apa;
            ap_buf[apbase + (size_t)i * 32 + cl + 16] = apb;
        }
        float dsum = apa + apb;
        dsum += __shfl_xor(dsum, 4);
        dsum += __shfl_xor(dsum, 8);
        dsum += __shfl_xor(dsum, 16);
        dsum += __shfl_xor(dsum, 32);
        if (lane == 0)
            atomicAdd(&denom_next[bb * 288 + i], dsum);
    }
}

extern "C" void kernel_launch(void* const* d_in, const int* in_sizes, int n_in,
                              void* d_out, int out_size, void* d_ws, size_t ws_size,
                              hipStream_t stream)
{
    const float* lambda_p = (const float*)d_in[0];
    const float* poses    = (const float*)d_in[1];
    const float* acts     = (const float*)d_in[2];
    const float* W        = (const float*)d_in[3];
    const float* beta_v   = (const float*)d_in[4];
    const float* beta_a   = (const float*)d_in[5];
    float* out = (float*)d_out;

    float* ws     = (float*)d_ws;
    float* Ptg    = ws;                     // 576*4608 = 2,654,208 floats
    float* actp   = Ptg + 2654208;          // 576*288  =   165,888
    float* ap_buf = actp + 165888;          // 576*9216 = 5,308,416
    float* Mpart  = ap_buf + 5308416;       // 2304*1152 = 2,654,208 (stats alias)
    float* denom0 = Mpart + 2654208;        // 4608
    float* denom1 = denom0 + 4608;          // 4608

    hipMemsetAsync(denom0, 0, 2 * 4608 * sizeof(float), stream);
    m_pass<0><<<2304, 128, 0, stream>>>(poses, acts, Ptg, actp, W, ap_buf, denom1, Mpart);
    f_pass<0><<<576, 64, 0, stream>>>(Mpart, beta_v, beta_a, lambda_p, out);
    e_pass<<<2304, 128, 0, stream>>>(Ptg, Mpart, W, ap_buf, denom0);
    m_pass<1><<<2304, 128, 0, stream>>>(poses, acts, Ptg, actp, W, ap_buf, denom0, Mpart);
    f_pass<0><<<576, 64, 0, stream>>>(Mpart, beta_v, beta_a, lambda_p, out);
    e_pass<<<2304, 128, 0, stream>>>(Ptg, Mpart, W, ap_buf, denom1);
    m_pass<2><<<2304, 128, 0, stream>>>(poses, acts, Ptg, actp, W, ap_buf, denom1, Mpart);
    f_pass<1><<<576, 64, 0, stream>>>(Mpart, beta_v, beta_a, lambda_p, out);
}